// Round 9
// baseline (1758.333 us; speedup 1.0000x reference)
//
#include <hip/hip_runtime.h>
#include <hip/hip_bf16.h>
#include <stdint.h>

// Problem constants (from reference)
#define B_      8
#define N_      16384
#define NPOINT  512
#define KNN_    16
#define C_      16

// Exact IEEE f32 ops — bit-match the numpy (ref=np) lowering:
//   p2/s2 : np.sum(v*v,-1)  -> pairwise small-n ASCENDING:  (x2+y2)+z2, no FMA
//   FPS d : np.sum(dd*dd,-1)-> ASCENDING:  (dx2+dy2)+dz2, no FMA
//   dot   : np.einsum unopt -> sum_of_products_contig_two remainder switch,
//           DESCENDING fallthrough:  ((sz*pz) + sy*py) + sx*px, no FMA
//   dist  : (s2 + p2) - 2*dot   elementwise, no FMA
__device__ __forceinline__ float fmulrn(float a, float b){ return __fmul_rn(a,b); }
__device__ __forceinline__ float faddrn(float a, float b){ return __fadd_rn(a,b); }
__device__ __forceinline__ float fsubrn(float a, float b){ return __fsub_rn(a,b); }

// ---------------------------------------------------------------------------
// Kernel 1: pack {x, y, z, p2} per point.  p2 = (x*x + y*y) + z*z  (ascending).
// ---------------------------------------------------------------------------
__global__ void prep_kernel(const float* __restrict__ x, float4* __restrict__ pts){
    int i = blockIdx.x * blockDim.x + threadIdx.x;   // 0 .. B_*N_-1
    if (i >= B_ * N_) return;
    const float4* x4 = (const float4*)x;             // x row = 16 floats = 4 float4
    float4 q = x4[(size_t)i * 4];                    // channels 0..3: x,y,z,c3
    float p2 = faddrn(faddrn(fmulrn(q.x,q.x), fmulrn(q.y,q.y)), fmulrn(q.z,q.z));
    pts[i] = make_float4(q.x, q.y, q.z, p2);
}

// ---------------------------------------------------------------------------
// Kernel 2: furthest point sampling, one block per batch.
// R5-R8 post-mortem: VGPR stuck at ~50 across every attribute change -> the
// float[16] arrays never became SSA scalars (stack allocas in scratch; rule
// #20). Each iteration re-streamed ~320 B/thread of scratch through L1/L2 =
// ~5k cyc/iter = the measured 1450us. Fix: NO ARRAYS — 64 macro-generated
// NAMED scalars (pure SSA, nothing for SROA to miss), waves_per_eu(4,4) for
// the 128-VGPR budget that fits the ~85-reg working set.
// ---------------------------------------------------------------------------
#define FPS_T   1024
#define FPS_NW  (FPS_T/64)     // 16 waves

#define FOR_SLOTS(F) F(0) F(1) F(2) F(3) F(4) F(5) F(6) F(7) \
                     F(8) F(9) F(10) F(11) F(12) F(13) F(14) F(15)

__global__ void __launch_bounds__(FPS_T)
__attribute__((amdgpu_waves_per_eu(4, 4)))
fps_kernel(const float4* __restrict__ pts, float4* __restrict__ s_out){
    __shared__ float    red_v[2][FPS_NW];
    __shared__ uint32_t red_i[2][FPS_NW];

    const int b    = blockIdx.x;
    const int tid  = threadIdx.x;
    const int lane = tid & 63;
    const int wv   = tid >> 6;
    const float4* P = pts + (size_t)b * N_;

    // 64 named scalar registers — no arrays, no allocas, no scratch.
#define DECL_SLOT(s) float px##s, py##s, pz##s, md##s;
    FOR_SLOTS(DECL_SLOT)
#undef DECL_SLOT

#define INIT_SLOT(s) { float4 q = P[(s) * FPS_T + tid]; \
        px##s = q.x; py##s = q.y; pz##s = q.z; md##s = 1e10f; }
    FOR_SLOTS(INIT_SLOT)
#undef INIT_SLOT

    float lx, ly, lz;
    {
        float4 q0 = P[0];                    // seed = index 0
        lx = q0.x; ly = q0.y; lz = q0.z;
        if (tid == 0) s_out[(size_t)b * NPOINT + 0] = q0;
    }

    for (int it = 1; it < NPOINT; ++it){
        float    bv = -1.0f;                 // all min_d >= 0
        uint32_t bi = 0;
        // slots ascend in global index -> strict > keeps first occurrence
#define DO_SLOT(s) { \
        float dx = fsubrn(px##s, lx); \
        float dy = fsubrn(py##s, ly); \
        float dz = fsubrn(pz##s, lz); \
        float d  = faddrn(faddrn(fmulrn(dx,dx), fmulrn(dy,dy)), fmulrn(dz,dz)); \
        md##s = fminf(md##s, d); \
        if (md##s > bv){ bv = md##s; bi = (uint32_t)((s) * FPS_T + tid); } }
        FOR_SLOTS(DO_SLOT)
#undef DO_SLOT

        // wave reduce: (max value, min index on ties) == first occurrence
        #pragma unroll
        for (int off = 1; off < 64; off <<= 1){
            float    ov = __shfl_xor(bv, off, 64);
            uint32_t oi = __shfl_xor(bi, off, 64);
            if (ov > bv || (ov == bv && oi < bi)){ bv = ov; bi = oi; }
        }
        const int par = it & 1;
        if (lane == 0){ red_v[par][wv] = bv; red_i[par][wv] = bi; }
        __syncthreads();
        float    gv = red_v[par][0];
        uint32_t gi = red_i[par][0];
        #pragma unroll
        for (int w = 1; w < FPS_NW; ++w){
            float    ov = red_v[par][w];
            uint32_t oi = red_i[par][w];
            if (ov > gv || (ov == gv && oi < gi)){ gv = ov; gi = oi; }
        }
        // winner broadcast: block-uniform index -> scalar load path
        uint32_t giu = (uint32_t)__builtin_amdgcn_readfirstlane((int)gi);
        float4 q = P[giu];
        lx = q.x; ly = q.y; lz = q.z;
        if (tid == 0) s_out[(size_t)b * NPOINT + it] = q;
    }
}

// ---------------------------------------------------------------------------
// Kernel 3: exact 16-NN per sample row (one wave per row, 4 rows per block).
//   dot  = ((sz*pz) + sy*py) + sx*px   [np.einsum contig_two DESCENDING tail]
//   dist = (s2 + p2) - 2*dot
// Total order = (monotone u32 key of dist, point index) packed into u64 —
// stable argsort ascending. Per-lane sorted top-16 insert cascade; 16-round
// head-consume wave merge.
// ---------------------------------------------------------------------------
__global__ void __launch_bounds__(256, 4)
knn_kernel(const float* __restrict__ x,
           const float4* __restrict__ pts,
           const float4* __restrict__ s_arr,
           float* __restrict__ out){
    const int wv   = threadIdx.x >> 6;
    const int lane = threadIdx.x & 63;
    const int blk  = blockIdx.x;            // 0 .. B_*NPOINT/4 - 1
    const int b    = blk >> 7;              // 128 blocks per batch
    const int p    = ((blk & 127) << 2) | wv;

    const float4 s = s_arr[(size_t)b * NPOINT + p];
    const float sx = s.x, sy = s.y, sz = s.z, s2 = s.w;
    const float4* P = pts + (size_t)b * N_;

    unsigned long long v[KNN_];
    #pragma unroll
    for (int j = 0; j < KNN_; ++j) v[j] = ~0ULL;

    #pragma unroll 1
    for (int j = 0; j < N_/64; ++j){
        const int n = (j << 6) | lane;
        float4 q = P[n];
        // numpy einsum remainder: DESCENDING index order, no FMA
        float dot = faddrn(faddrn(fmulrn(sz, q.z), fmulrn(sy, q.y)), fmulrn(sx, q.x));
        float d = fsubrn(faddrn(s2, q.w), fmulrn(2.0f, dot));
        uint32_t bits = __float_as_uint(d);
        uint32_t key  = bits ^ (((uint32_t)((int32_t)bits >> 31)) | 0x80000000u);
        unsigned long long c = ((unsigned long long)key << 32) | (uint32_t)n;
        if (c < v[KNN_-1]){
            #pragma unroll
            for (int t = 0; t < KNN_; ++t){
                unsigned long long lo = (c < v[t]) ? c : v[t];
                unsigned long long hi = (c < v[t]) ? v[t] : c;
                v[t] = lo; c = hi;
            }
        }
    }

    // merge: 16 rounds of wave-min over per-lane heads; winner lane consumes.
    uint32_t myidx = 0;
    const int myr = lane >> 2;
    #pragma unroll 1
    for (int r = 0; r < KNN_; ++r){
        unsigned long long h = v[0];
        unsigned long long g = h;
        #pragma unroll
        for (int off = 1; off < 64; off <<= 1){
            unsigned long long o = __shfl_xor(g, off, 64);
            if (o < g) g = o;
        }
        if (h == g){                          // unique winner (idx is unique)
            #pragma unroll
            for (int t = 0; t < KNN_-1; ++t) v[t] = v[t+1];
            v[KNN_-1] = ~0ULL;
        }
        if (myr == r) myidx = (uint32_t)g;    // keep idx of my output row
    }

    // gather + write: lane l handles neighbor r=l>>2, channels 4*(l&3)..+3
    const int c4 = lane & 3;
    const float4* X4 = (const float4*)x;
    float4 valq = X4[((size_t)b * N_ + myidx) * 4 + c4];
    float4* O4 = (float4*)out;
    O4[(((size_t)b * NPOINT + p) * KNN_ + myr) * 4 + c4] = valq;
}

// ---------------------------------------------------------------------------
extern "C" void kernel_launch(void* const* d_in, const int* in_sizes, int n_in,
                              void* d_out, int out_size, void* d_ws, size_t ws_size,
                              hipStream_t stream) {
    const float* x = (const float*)d_in[0];
    float* out = (float*)d_out;

    // workspace layout: [B_*N_ float4 packed points][B_*NPOINT float4 samples]
    const size_t pts_bytes = (size_t)B_ * N_ * sizeof(float4);
    const size_t s_bytes   = (size_t)B_ * NPOINT * sizeof(float4);
    if (ws_size < pts_bytes + s_bytes) return;   // visible failure if ws too small
    float4* pts   = (float4*)d_ws;
    float4* s_arr = (float4*)((char*)d_ws + pts_bytes);

    prep_kernel<<<(B_*N_ + 255)/256, 256, 0, stream>>>(x, pts);
    fps_kernel<<<B_, FPS_T, 0, stream>>>(pts, s_arr);
    knn_kernel<<<(B_*NPOINT)/4, 256, 0, stream>>>(x, pts, s_arr, out);
}

// Round 10
// 1285.041 us; speedup vs baseline: 1.3683x; 1.3683x over previous
//
#include <hip/hip_runtime.h>
#include <hip/hip_bf16.h>
#include <stdint.h>

// Problem constants (from reference)
#define B_      8
#define N_      16384
#define NPOINT  512
#define KNN_    16
#define C_      16

// Exact IEEE f32 ops — bit-match the numpy (ref=np) lowering:
//   p2/s2 : np.sum(v*v,-1)  -> pairwise small-n ASCENDING:  (x2+y2)+z2, no FMA
//   FPS d : np.sum(dd*dd,-1)-> ASCENDING:  (dx2+dy2)+dz2, no FMA
//   dot   : np.einsum unopt -> sum_of_products_contig_two remainder switch,
//           DESCENDING fallthrough:  ((sz*pz) + sy*py) + sx*px, no FMA
//   dist  : (s2 + p2) - 2*dot   elementwise, no FMA
__device__ __forceinline__ float fmulrn(float a, float b){ return __fmul_rn(a,b); }
__device__ __forceinline__ float faddrn(float a, float b){ return __fadd_rn(a,b); }
__device__ __forceinline__ float fsubrn(float a, float b){ return __fsub_rn(a,b); }

// ---------------------------------------------------------------------------
// Kernel 1: pack {x, y, z, p2} per point.  p2 = (x*x + y*y) + z*z  (ascending).
// ---------------------------------------------------------------------------
__global__ void prep_kernel(const float* __restrict__ x, float4* __restrict__ pts){
    int i = blockIdx.x * blockDim.x + threadIdx.x;   // 0 .. B_*N_-1
    if (i >= B_ * N_) return;
    const float4* x4 = (const float4*)x;             // x row = 16 floats = 4 float4
    float4 q = x4[(size_t)i * 4];                    // channels 0..3: x,y,z,c3
    float p2 = faddrn(faddrn(fmulrn(q.x,q.x), fmulrn(q.y,q.y)), fmulrn(q.z,q.z));
    pts[i] = make_float4(q.x, q.y, q.z, p2);
}

// ---------------------------------------------------------------------------
// Kernel 2: furthest point sampling, one block per batch.
// R5-R9 diagnosis: coord loads from const-restrict memory are treated as
// invariant-rematerializable -> allocator re-loads them EVERY iteration (or
// spills when pinned under a 64-VGPR occupancy target) = ~256KB/CU/iter via
// L2 = the invariant 1450us. This round closes BOTH escape hatches:
//   named scalars (no allocas)  +  volatile-asm pins (asm results cannot be
//   rematerialized)             +  waves_per_eu(4,4) (128-VGPR budget, no
//   spill pressure).
// Reduce: u64 key {hi = f32 bits of min_d (>=0, monotone), lo = ~idx} ->
// max(key) == (max value, min index) == numpy first-occurrence argmax.
// Lane-parallel block scan: lane l re-reads wave (l&15)'s LDS entry, 6-step
// shfl-xor max (replication-safe), so every thread gets the winner cheaply.
// ---------------------------------------------------------------------------
#define FPS_T   1024
#define FPS_NW  (FPS_T/64)     // 16 waves

#define FOR_SLOTS(F) F(0) F(1) F(2) F(3) F(4) F(5) F(6) F(7) \
                     F(8) F(9) F(10) F(11) F(12) F(13) F(14) F(15)

__global__ void __launch_bounds__(FPS_T)
__attribute__((amdgpu_waves_per_eu(4, 4)))
fps_kernel(const float4* __restrict__ pts, float4* __restrict__ s_out){
    __shared__ unsigned long long red[2][FPS_NW];

    const int b    = blockIdx.x;
    const int tid  = threadIdx.x;
    const int lane = tid & 63;
    const int wv   = tid >> 6;
    const float4* P = pts + (size_t)b * N_;

    // 64 named scalar registers — no arrays, no allocas.
#define DECL_SLOT(s) float px##s, py##s, pz##s, md##s;
    FOR_SLOTS(DECL_SLOT)
#undef DECL_SLOT

#define INIT_SLOT(s) { float4 q = P[(s) * FPS_T + tid]; \
        px##s = q.x; py##s = q.y; pz##s = q.z; md##s = 1e10f; }
    FOR_SLOTS(INIT_SLOT)
#undef INIT_SLOT

    // Pin each coordinate: a volatile-asm result is neither rematerializable
    // nor duplicable, so the value MUST stay live (and with the 128-VGPR
    // budget from waves_per_eu(4,4) there is no pressure to spill it).
#define PIN_SLOT(s) asm volatile("" : "+v"(px##s), "+v"(py##s), "+v"(pz##s));
    FOR_SLOTS(PIN_SLOT)
#undef PIN_SLOT

    float lx, ly, lz;
    {
        float4 q0 = P[0];                    // seed = index 0
        lx = q0.x; ly = q0.y; lz = q0.z;
        if (tid == 0) s_out[(size_t)b * NPOINT + 0] = q0;
    }

    for (int it = 1; it < NPOINT; ++it){
        float    bv = -1.0f;                 // all min_d >= 0
        uint32_t bi = 0;
        // slots ascend in global index -> strict > keeps first occurrence
#define DO_SLOT(s) { \
        float dx = fsubrn(px##s, lx); \
        float dy = fsubrn(py##s, ly); \
        float dz = fsubrn(pz##s, lz); \
        float d  = faddrn(faddrn(fmulrn(dx,dx), fmulrn(dy,dy)), fmulrn(dz,dz)); \
        md##s = fminf(md##s, d); \
        if (md##s > bv){ bv = md##s; bi = (uint32_t)((s) * FPS_T + tid); } }
        FOR_SLOTS(DO_SLOT)
#undef DO_SLOT

        // u64 key: (max value, min index) via single 64-bit max
        unsigned long long k =
            ((unsigned long long)__float_as_uint(bv) << 32) |
            (unsigned long long)(~bi);
        #pragma unroll
        for (int off = 1; off < 64; off <<= 1){
            unsigned long long o = __shfl_xor(k, off, 64);
            if (o > k) k = o;
        }
        const int par = it & 1;
        if (lane == 0) red[par][wv] = k;
        __syncthreads();
        // lane-parallel scan: entry (lane&15), replicated 4x; xor-max is safe
        unsigned long long g = red[par][lane & 15];
        #pragma unroll
        for (int off = 1; off < 64; off <<= 1){
            unsigned long long o = __shfl_xor(g, off, 64);
            if (o > g) g = o;
        }
        uint32_t gi  = ~((uint32_t)g);       // lo field was ~idx
        uint32_t giu = (uint32_t)__builtin_amdgcn_readfirstlane((int)gi);
        float4 q = P[giu];                   // block-uniform scalar load
        lx = q.x; ly = q.y; lz = q.z;
        if (tid == 0) s_out[(size_t)b * NPOINT + it] = q;
    }
}

// ---------------------------------------------------------------------------
// Kernel 3: exact 16-NN per sample row (one wave per row, 4 rows per block).
//   dot  = ((sz*pz) + sy*py) + sx*px   [np.einsum contig_two DESCENDING tail]
//   dist = (s2 + p2) - 2*dot
// Total order = (monotone u32 key, idx) packed u64. R9 post-mortem: the
// u64 v[16] array was almost certainly alloca'd (rule #20) -> every insert
// cascade did ~256B of scratch RMW -> ~280us. Fix: 16 NAMED u64 scalars +
// macro cascade, waves_per_eu(4,4) so the ~75-reg working set isn't spilled.
// ---------------------------------------------------------------------------
#define FOR_V(F) F(0) F(1) F(2) F(3) F(4) F(5) F(6) F(7) \
                 F(8) F(9) F(10) F(11) F(12) F(13) F(14) F(15)

__global__ void __launch_bounds__(256)
__attribute__((amdgpu_waves_per_eu(4, 4)))
knn_kernel(const float* __restrict__ x,
           const float4* __restrict__ pts,
           const float4* __restrict__ s_arr,
           float* __restrict__ out){
    const int wv   = threadIdx.x >> 6;
    const int lane = threadIdx.x & 63;
    const int blk  = blockIdx.x;            // 0 .. B_*NPOINT/4 - 1
    const int b    = blk >> 7;              // 128 blocks per batch
    const int p    = ((blk & 127) << 2) | wv;

    const float4 s = s_arr[(size_t)b * NPOINT + p];
    const float sx = s.x, sy = s.y, sz = s.z, s2 = s.w;
    const float4* P = pts + (size_t)b * N_;

#define DECLV(t) unsigned long long v##t = ~0ULL;
    FOR_V(DECLV)
#undef DECLV

    #pragma unroll 1
    for (int j = 0; j < N_/64; ++j){
        const int n = (j << 6) | lane;
        float4 q = P[n];
        // numpy einsum remainder: DESCENDING index order, no FMA
        float dot = faddrn(faddrn(fmulrn(sz, q.z), fmulrn(sy, q.y)), fmulrn(sx, q.x));
        float d = fsubrn(faddrn(s2, q.w), fmulrn(2.0f, dot));
        uint32_t bits = __float_as_uint(d);
        uint32_t key  = bits ^ (((uint32_t)((int32_t)bits >> 31)) | 0x80000000u);
        unsigned long long c = ((unsigned long long)key << 32) | (uint32_t)n;
        if (c < v15){
#define INS(t) { bool lt = c < v##t; \
                 unsigned long long lo = lt ? c : v##t; \
                 unsigned long long hi = lt ? v##t : c; \
                 v##t = lo; c = hi; }
            FOR_V(INS)
#undef INS
        }
    }

    // merge: 16 rounds of wave-min over per-lane heads; winner lane consumes.
    uint32_t myidx = 0;
    const int myr = lane >> 2;
    #pragma unroll 1
    for (int r = 0; r < KNN_; ++r){
        unsigned long long h = v0;
        unsigned long long g = h;
        #pragma unroll
        for (int off = 1; off < 64; off <<= 1){
            unsigned long long o = __shfl_xor(g, off, 64);
            if (o < g) g = o;
        }
        if (h == g){                          // unique winner (idx is unique)
            v0=v1; v1=v2; v2=v3; v3=v4; v4=v5; v5=v6; v6=v7; v7=v8;
            v8=v9; v9=v10; v10=v11; v11=v12; v12=v13; v13=v14; v14=v15;
            v15=~0ULL;
        }
        if (myr == r) myidx = (uint32_t)g;    // keep idx of my output row
    }

    // gather + write: lane l handles neighbor r=l>>2, channels 4*(l&3)..+3
    const int c4 = lane & 3;
    const float4* X4 = (const float4*)x;
    float4 valq = X4[((size_t)b * N_ + myidx) * 4 + c4];
    float4* O4 = (float4*)out;
    O4[(((size_t)b * NPOINT + p) * KNN_ + myr) * 4 + c4] = valq;
}

// ---------------------------------------------------------------------------
extern "C" void kernel_launch(void* const* d_in, const int* in_sizes, int n_in,
                              void* d_out, int out_size, void* d_ws, size_t ws_size,
                              hipStream_t stream) {
    const float* x = (const float*)d_in[0];
    float* out = (float*)d_out;

    // workspace layout: [B_*N_ float4 packed points][B_*NPOINT float4 samples]
    const size_t pts_bytes = (size_t)B_ * N_ * sizeof(float4);
    const size_t s_bytes   = (size_t)B_ * NPOINT * sizeof(float4);
    if (ws_size < pts_bytes + s_bytes) return;   // visible failure if ws too small
    float4* pts   = (float4*)d_ws;
    float4* s_arr = (float4*)((char*)d_ws + pts_bytes);

    prep_kernel<<<(B_*N_ + 255)/256, 256, 0, stream>>>(x, pts);
    fps_kernel<<<B_, FPS_T, 0, stream>>>(pts, s_arr);
    knn_kernel<<<(B_*NPOINT)/4, 256, 0, stream>>>(x, pts, s_arr, out);
}